// Round 2
// 13711.862 us; speedup vs baseline: 1.1360x; 1.1360x over previous
//
#include <hip/hip_runtime.h>
#include <math.h>

#define B_ 4
#define S_ 512
#define T_ 2048        // B_*S_
#define D_ 768
#define H_ 12
#define DH_ 64
#define FF_ 3072
#define G_ 4096        // 2*DHID
#define DHID_ 2048
#define E_ 8
#define CAP_ 256
#define V_ 50258
#define NL_ 6

__device__ __forceinline__ float gelu_tanh_f(float x) {
    float x3 = x * x * x;
    return 0.5f * x * (1.0f + tanhf(0.7978845608028654f * (x + 0.044715f * x3)));
}
__device__ __forceinline__ float gelu_exact_f(float x) {
    return 0.5f * x * (1.0f + erff(x * 0.7071067811865475f));
}

// ---------------- embedding ----------------
__global__ __launch_bounds__(256) void embed_kernel(
    const int* __restrict__ ids, const float* __restrict__ wte,
    const float* __restrict__ wpe, float* __restrict__ x) {
    int t = blockIdx.x;
    int id = ids[t];
    int s = t & (S_ - 1);
    const float* wt = wte + (long long)id * D_;
    const float* wp = wpe + (long long)s * D_;
    float* o = x + (long long)t * D_;
    for (int c = threadIdx.x; c < D_; c += 256) o[c] = wt[c] + wp[c];
}

// ---------------- layernorm (row = 768) ----------------
__global__ __launch_bounds__(256) void ln_kernel(
    const float* __restrict__ X, const float* __restrict__ g,
    const float* __restrict__ bb, float* __restrict__ out) {
    __shared__ float red[256];
    int t = blockIdx.x, tid = threadIdx.x;
    const float* x = X + (long long)t * D_;
    float v0 = x[tid], v1 = x[tid + 256], v2 = x[tid + 512];
    red[tid] = v0 + v1 + v2;
    __syncthreads();
    for (int o = 128; o; o >>= 1) { if (tid < o) red[tid] += red[tid + o]; __syncthreads(); }
    float mean = red[0] * (1.0f / D_);
    __syncthreads();
    float d0 = v0 - mean, d1 = v1 - mean, d2 = v2 - mean;
    red[tid] = d0 * d0 + d1 * d1 + d2 * d2;
    __syncthreads();
    for (int o = 128; o; o >>= 1) { if (tid < o) red[tid] += red[tid + o]; __syncthreads(); }
    float r = rsqrtf(red[0] * (1.0f / D_) + 1e-5f);
    float* op = out + (long long)t * D_;
    op[tid]       = d0 * r * g[tid]       + bb[tid];
    op[tid + 256] = d1 * r * g[tid + 256] + bb[tid + 256];
    op[tid + 512] = d2 * r * g[tid + 512] + bb[tid + 512];
}

// ---------------- rmsnorm ----------------
__global__ __launch_bounds__(256) void rms_kernel(
    const float* __restrict__ X, const float* __restrict__ g, float* __restrict__ out) {
    __shared__ float red[256];
    int t = blockIdx.x, tid = threadIdx.x;
    const float* x = X + (long long)t * D_;
    float v0 = x[tid], v1 = x[tid + 256], v2 = x[tid + 512];
    red[tid] = v0 * v0 + v1 * v1 + v2 * v2;
    __syncthreads();
    for (int o = 128; o; o >>= 1) { if (tid < o) red[tid] += red[tid + o]; __syncthreads(); }
    float r = rsqrtf(red[0] * (1.0f / D_) + 1e-6f);
    float* op = out + (long long)t * D_;
    op[tid]       = v0 * r * g[tid];
    op[tid + 256] = v1 * r * g[tid + 256];
    op[tid + 512] = v2 * r * g[tid + 512];
}

// ---------------- generic fp32 GEMM: C = act(A@B + bias) (+ Res) ----------------
// 128x128 tile, 256 threads, 8x8 acc/thread (two 4x4 quadrants per dim).
// A: [M,K] lda. B: !BT -> [K,N] ldb (N must be %128==0!) ; BT -> [N,K] ldb(=K), N guarded.
// Res/C: [M,N] ldc. gridDim.z batches (expert) with element strides sA,sB,sBias,sC.
// Requires: M % 128 == 0, K % 16 == 0, lda/ldb % 4 == 0.
template <int ACT, bool BIAS, bool RESID, bool BT>
__global__ __launch_bounds__(256) void gemm_kernel(
    const float* __restrict__ A, int lda, long long sA,
    const float* __restrict__ Bm, int ldb, long long sB,
    const float* __restrict__ bias, long long sBias,
    const float* __restrict__ Res,
    float* __restrict__ C, int ldc, long long sC,
    int M, int N, int K) {
    const int bz = blockIdx.z;
    const float* Ap = A + (long long)bz * sA;
    const float* Bp = Bm + (long long)bz * sB;
    const float* biasp = BIAS ? bias + (long long)bz * sBias : nullptr;
    const float* Resp = RESID ? Res + (long long)bz * sC : nullptr;
    float* Cp = C + (long long)bz * sC;

    const int m0 = blockIdx.y * 128;
    const int n0 = blockIdx.x * 128;
    const int tid = threadIdx.x;
    const int tx = tid & 15, ty = tid >> 4;

    // rows padded to 132 floats: 528 B (16B-aligned) -> ds_read_b128 frags
    __shared__ float As[16][132];
    __shared__ float Bs[16][132];

    float acc[8][8] = {};

    const int amr = tid >> 2;        // staging row 0..63 (A and B^T)
    const int akg = (tid & 3) * 4;   // staging k-group
    const int bkr = tid >> 5;        // B staging k row 0..7
    const int bnc = (tid & 31) * 4;  // B staging col

    for (int k0 = 0; k0 < K; k0 += 16) {
        {   // A tile 128x16 -> As[k][m] (transposed; writes <=2-way aliased)
            const float* Ab = Ap + (long long)(m0 + amr) * lda + k0 + akg;
            float4 a0 = *(const float4*)Ab;
            float4 a1 = *(const float4*)(Ab + (long long)64 * lda);
            As[akg + 0][amr] = a0.x; As[akg + 1][amr] = a0.y;
            As[akg + 2][amr] = a0.z; As[akg + 3][amr] = a0.w;
            As[akg + 0][amr + 64] = a1.x; As[akg + 1][amr + 64] = a1.y;
            As[akg + 2][amr + 64] = a1.z; As[akg + 3][amr + 64] = a1.w;
        }
        if (!BT) {  // B tile 16x128, natural layout, b128 writes
            const float* Bb = Bp + (long long)(k0 + bkr) * ldb + n0 + bnc;
            *(float4*)&Bs[bkr][bnc]     = *(const float4*)Bb;
            *(float4*)&Bs[bkr + 8][bnc] = *(const float4*)(Bb + (long long)8 * ldb);
        } else {    // B^T tile: rows n (guarded vs N), cols k
            float4 b0 = make_float4(0.f, 0.f, 0.f, 0.f), b1 = b0;
            if (n0 + amr < N)
                b0 = *(const float4*)(Bp + (long long)(n0 + amr) * ldb + k0 + akg);
            if (n0 + amr + 64 < N)
                b1 = *(const float4*)(Bp + (long long)(n0 + amr + 64) * ldb + k0 + akg);
            Bs[akg + 0][amr] = b0.x; Bs[akg + 1][amr] = b0.y;
            Bs[akg + 2][amr] = b0.z; Bs[akg + 3][amr] = b0.w;
            Bs[akg + 0][amr + 64] = b1.x; Bs[akg + 1][amr + 64] = b1.y;
            Bs[akg + 2][amr + 64] = b1.z; Bs[akg + 3][amr + 64] = b1.w;
        }
        __syncthreads();
#pragma unroll
        for (int k = 0; k < 16; ++k) {
            // A frags: 4 distinct addrs/wave -> broadcast. B frags: <=2-way (free).
            float4 a0 = *(const float4*)&As[k][ty * 4];
            float4 a1 = *(const float4*)&As[k][64 + ty * 4];
            float4 b0 = *(const float4*)&Bs[k][tx * 4];
            float4 b1 = *(const float4*)&Bs[k][64 + tx * 4];
            float av[8] = {a0.x, a0.y, a0.z, a0.w, a1.x, a1.y, a1.z, a1.w};
            float bv[8] = {b0.x, b0.y, b0.z, b0.w, b1.x, b1.y, b1.z, b1.w};
#pragma unroll
            for (int i = 0; i < 8; ++i)
#pragma unroll
                for (int j = 0; j < 8; ++j) acc[i][j] += av[i] * bv[j];
        }
        __syncthreads();
    }

#pragma unroll
    for (int i = 0; i < 8; ++i) {
        int m = m0 + ((i & 4) ? 64 : 0) + ty * 4 + (i & 3);
#pragma unroll
        for (int j = 0; j < 8; ++j) {
            int n = n0 + ((j & 4) ? 64 : 0) + tx * 4 + (j & 3);
            if (n < N) {
                float v = acc[i][j];
                if (BIAS) v += biasp[n];
                if (ACT == 1) v = gelu_tanh_f(v);
                if (RESID) v += Resp[(long long)m * ldc + n];
                Cp[(long long)m * ldc + n] = v;
            }
        }
    }
}

template <int ACT, bool BIAS, bool RESID, bool BT>
static void launch_gemm(hipStream_t st, const float* A, int lda, long long sA,
                        const float* Bm, int ldb, long long sB,
                        const float* bias, long long sBias, const float* Res,
                        float* C, int ldc, long long sC, int M, int N, int K, int Z) {
    dim3 g((N + 127) / 128, M / 128, Z);
    gemm_kernel<ACT, BIAS, RESID, BT><<<g, 256, 0, st>>>(
        A, lda, sA, Bm, ldb, sB, bias, sBias, Res, C, ldc, sC, M, N, K);
}

// ---------------- attention: scores + softmax ----------------
__global__ __launch_bounds__(256) void attn_scores_kernel(
    const float* __restrict__ qkv, float* __restrict__ P) {
    int q = blockIdx.x, h = blockIdx.y, b = blockIdx.z;
    int tid = threadIdx.x;
    __shared__ float4 qv[16];
    __shared__ float red[256];
    const float* qrow = qkv + ((long long)(b * S_ + q)) * (3 * D_) + h * DH_;
    if (tid < 16) qv[tid] = *(const float4*)(qrow + tid * 4);
    __syncthreads();
    float sc[2];
#pragma unroll
    for (int r = 0; r < 2; ++r) {
        int k = tid + r * 256;
        float s = -1e30f;
        if (k <= q) {
            const float* krow = qkv + ((long long)(b * S_ + k)) * (3 * D_) + D_ + h * DH_;
            float dot = 0.f;
#pragma unroll
            for (int i = 0; i < 16; ++i) {
                float4 kv = *(const float4*)(krow + i * 4);
                float4 qq = qv[i];
                dot += qq.x * kv.x + qq.y * kv.y + qq.z * kv.z + qq.w * kv.w;
            }
            s = dot * 0.125f;
        }
        sc[r] = s;
    }
    float mx = fmaxf(sc[0], sc[1]);
    red[tid] = mx; __syncthreads();
    for (int o = 128; o; o >>= 1) { if (tid < o) red[tid] = fmaxf(red[tid], red[tid + o]); __syncthreads(); }
    mx = red[0]; __syncthreads();
    float e0 = (sc[0] > -1e29f) ? expf(sc[0] - mx) : 0.f;
    float e1 = (sc[1] > -1e29f) ? expf(sc[1] - mx) : 0.f;
    red[tid] = e0 + e1; __syncthreads();
    for (int o = 128; o; o >>= 1) { if (tid < o) red[tid] += red[tid + o]; __syncthreads(); }
    float inv = 1.0f / red[0];
    float* pr = P + (((long long)(b * H_ + h) * S_) + q) * S_;
    pr[tid] = e0 * inv;
    pr[tid + 256] = e1 * inv;
}

// ---------------- attention: P @ V ----------------
__global__ __launch_bounds__(64) void attn_pv_kernel(
    const float* __restrict__ qkv, const float* __restrict__ P, float* __restrict__ O) {
    int q = blockIdx.x, h = blockIdx.y, b = blockIdx.z;
    int d = threadIdx.x;
    const float* pr = P + (((long long)(b * H_ + h) * S_) + q) * S_;
    const float* vb = qkv + (long long)b * S_ * (3 * D_) + 2 * D_ + h * DH_ + d;
    float acc = 0.f;
    for (int k = 0; k <= q; ++k) acc += pr[k] * vb[(long long)k * (3 * D_)];
    O[((long long)(b * S_ + q)) * D_ + h * DH_ + d] = acc;
}

// ---------------- GLU: out[r,c] = h[r,c] * gelu_exact(h[r,2048+c]) ----------------
__global__ __launch_bounds__(256) void glu_kernel(
    const float* __restrict__ hb, float* __restrict__ ob, long long rows) {
    long long i = (long long)blockIdx.x * 256 + threadIdx.x;
    long long r = i >> 11;
    int c = (int)(i & (DHID_ - 1));
    float a = hb[r * G_ + c];
    float g = hb[r * G_ + DHID_ + c];
    ob[i] = a * gelu_exact_f(g);
}

// ---------------- MoE gating ----------------
__global__ __launch_bounds__(256) void moe_gate_kernel(
    const float* __restrict__ t0, const float* __restrict__ wg,
    int* __restrict__ idx1, int* __restrict__ idx2,
    float* __restrict__ g1o, float* __restrict__ g2o, float* __restrict__ red) {
    __shared__ float sred[17];
    int tid = threadIdx.x;
    if (tid < 17) sred[tid] = 0.f;
    __syncthreads();
    int t = blockIdx.x * 256 + tid;
    const float* xr = t0 + (long long)t * D_;
    float lg[E_];
#pragma unroll
    for (int e = 0; e < E_; ++e) lg[e] = 0.f;
    for (int i = 0; i < D_; ++i) {
        float xv = xr[i];
        const float* w = wg + i * E_;
#pragma unroll
        for (int e = 0; e < E_; ++e) lg[e] += xv * w[e];
    }
    float mx = lg[0];
#pragma unroll
    for (int e = 1; e < E_; ++e) mx = fmaxf(mx, lg[e]);
    float pe[E_], sum = 0.f;
#pragma unroll
    for (int e = 0; e < E_; ++e) { pe[e] = expf(lg[e] - mx); sum += pe[e]; }
    float lse = mx + logf(sum);
    float inv = 1.0f / sum;
#pragma unroll
    for (int e = 0; e < E_; ++e) pe[e] *= inv;
    int i1 = 0; float p1 = pe[0];
#pragma unroll
    for (int e = 1; e < E_; ++e) if (pe[e] > p1) { p1 = pe[e]; i1 = e; }
    int i2 = 0; float p2 = -1.f;
#pragma unroll
    for (int e = 0; e < E_; ++e) if (e != i1 && pe[e] > p2) { p2 = pe[e]; i2 = e; }
    float denom = p1 + p2 + 1e-9f;
    float g1 = p1 / denom;
    float keep = (p2 > 0.2f) ? 1.f : 0.f;
    float g2 = (p2 / denom) * keep;
    idx1[t] = i1; idx2[t] = i2; g1o[t] = g1; g2o[t] = g2;
    atomicAdd(&sred[i1], 1.0f);
#pragma unroll
    for (int e = 0; e < E_; ++e) atomicAdd(&sred[8 + e], pe[e]);
    atomicAdd(&sred[16], lse * lse);
    __syncthreads();
    if (tid < 17) atomicAdd(&red[tid], sred[tid]);
}

__global__ void aux_finalize_kernel(const float* __restrict__ red, float* __restrict__ aux) {
    if (threadIdx.x == 0 && blockIdx.x == 0) {
        float bal = 0.f;
        for (int e = 0; e < E_; ++e) bal += (red[e] / (float)T_) * (red[8 + e] / (float)T_);
        bal *= 8.f;  // mean over E (×1/8) then × E*E (=64)
        float z = red[16] / (float)T_;
        aux[0] += 0.01f * bal + 0.001f * z;
    }
}

// ---------------- capacity scan (one lane per (b,e)) ----------------
__global__ __launch_bounds__(64) void moe_scan_kernel(
    const int* __restrict__ idx1, const int* __restrict__ idx2, const float* __restrict__ g2,
    int* __restrict__ c1p, int* __restrict__ c2p, int* __restrict__ slot) {
    __shared__ int s1[T_];
    __shared__ int s2[T_];
    __shared__ unsigned char sk[T_];
    int tid = threadIdx.x;
    for (int i = tid; i < T_; i += 64) {
        s1[i] = idx1[i]; s2[i] = idx2[i]; sk[i] = (g2[i] > 0.f) ? 1 : 0;
    }
    __syncthreads();
    if (tid < 32) {
        int b = tid >> 3, e = tid & 7;
        int base = b * S_;
        int cnt = 0;
        for (int s = 0; s < S_; ++s) {
            int t = base + s;
            if (s1[t] == e) {
                int p = cnt++;
                if (p < CAP_) { c1p[t] = p; slot[(e * B_ + b) * CAP_ + p] = t; }
                else c1p[t] = -1;
            }
        }
        int cnt2 = cnt;  // second choices start after ALL (uncapped) first choices
        for (int s = 0; s < S_; ++s) {
            int t = base + s;
            if (s2[t] == e) {
                if (sk[t]) {
                    int p = cnt2++;
                    if (p < CAP_) { c2p[t] = p; slot[(e * B_ + b) * CAP_ + p] = t; }
                    else c2p[t] = -1;
                } else c2p[t] = -1;
            }
        }
    }
}

// ---------------- dispatch gather ----------------
__global__ __launch_bounds__(256) void moe_gather_kernel(
    const float* __restrict__ t0, const int* __restrict__ slot, float* __restrict__ xin) {
    int sidx = blockIdx.x;
    int tok = slot[sidx];
    float* o = xin + (long long)sidx * D_;
    if (tok >= 0) {
        const float* src = t0 + (long long)tok * D_;
        for (int c = threadIdx.x; c < D_; c += 256) o[c] = src[c];
    } else {
        for (int c = threadIdx.x; c < D_; c += 256) o[c] = 0.f;
    }
}

// ---------------- combine: x1 += g1*eout[slot1] + g2*eout[slot2] ----------------
__global__ __launch_bounds__(256) void moe_combine_kernel(
    const float* __restrict__ eout, const int* __restrict__ idx1, const int* __restrict__ idx2,
    const int* __restrict__ c1p, const int* __restrict__ c2p,
    const float* __restrict__ g1, const float* __restrict__ g2, float* __restrict__ x1) {
    int t = blockIdx.x;
    int b = t >> 9;
    int i1 = idx1[t], i2 = idx2[t], c1 = c1p[t], c2 = c2p[t];
    float w1 = g1[t], w2 = g2[t];
    const float* r1 = (c1 >= 0) ? eout + ((long long)(i1 * B_ + b) * CAP_ + c1) * D_ : nullptr;
    const float* r2 = (c2 >= 0 && w2 > 0.f) ? eout + ((long long)(i2 * B_ + b) * CAP_ + c2) * D_ : nullptr;
    float* xr = x1 + (long long)t * D_;
    for (int c = threadIdx.x; c < D_; c += 256) {
        float y = 0.f;
        if (r1) y += w1 * r1[c];
        if (r2) y += w2 * r2[c];
        xr[c] += y;
    }
}

__global__ __launch_bounds__(256) void add_kernel(
    float* __restrict__ a, const float* __restrict__ b, int n) {
    int i = blockIdx.x * 256 + threadIdx.x;
    if (i < n) a[i] += b[i];
}

__global__ void write_aux_kernel(float* __restrict__ dst, const float* __restrict__ aux) {
    if (threadIdx.x == 0) dst[0] = aux[0];
}

// =================================================================
extern "C" void kernel_launch(void* const* d_in, const int* in_sizes, int n_in,
                              void* d_out, int out_size, void* d_ws, size_t ws_size,
                              hipStream_t stream) {
    (void)in_sizes; (void)n_in; (void)out_size; (void)ws_size;
    const int*   ids    = (const int*)d_in[0];
    const float* wte    = (const float*)d_in[2];
    const float* wpe    = (const float*)d_in[3];
    const float* ln1_g  = (const float*)d_in[4];
    const float* ln1_b  = (const float*)d_in[5];
    const float* w_qkv  = (const float*)d_in[6];
    const float* b_qkv  = (const float*)d_in[7];
    const float* w_ao   = (const float*)d_in[8];
    const float* b_ao   = (const float*)d_in[9];
    const float* ln2_g  = (const float*)d_in[10];
    const float* ln2_b  = (const float*)d_in[11];
    const float* w_fc   = (const float*)d_in[12];
    const float* b_fc   = (const float*)d_in[13];
    const float* w_mp   = (const float*)d_in[14];
    const float* b_mp   = (const float*)d_in[15];
    const float* lnf_g  = (const float*)d_in[16];
    const float* lnf_b  = (const float*)d_in[17];
    const float* ffb_g  = (const float*)d_in[18];
    const float* ffb_w1 = (const float*)d_in[19];
    const float* ffb_b1 = (const float*)d_in[20];
    const float* ffb_w2 = (const float*)d_in[21];
    const float* ffb_b2 = (const float*)d_in[22];
    const float* moe_g  = (const float*)d_in[23];
    const float* w_gate = (const float*)d_in[24];
    const float* we1    = (const float*)d_in[25];
    const float* be1    = (const float*)d_in[26];
    const float* we2    = (const float*)d_in[27];
    const float* be2    = (const float*)d_in[28];
    const float* ffa_g  = (const float*)d_in[29];
    const float* ffa_w1 = (const float*)d_in[30];
    const float* ffa_b1 = (const float*)d_in[31];
    const float* ffa_w2 = (const float*)d_in[32];
    const float* ffa_b2 = (const float*)d_in[33];

    float* out = (float*)d_out;

    // ---- ws: final-LN output + gating state (~6.4 MB) ----
    float* xf   = (float*)d_ws;              // T*D
    float* aux  = xf + (long long)T_ * D_;   // [0] accumulator (pad to 4)
    float* red  = aux + 4;                   // 17 used (pad to 32)
    int*   idx1 = (int*)(red + 32);          // T
    int*   idx2 = idx1 + T_;                 // T
    int*   c1p  = idx2 + T_;                 // T
    int*   c2p  = c1p + T_;                  // T
    float* g1v  = (float*)(c2p + T_);        // T
    float* g2v  = g1v + T_;                  // T
    int*   slot = (int*)(g2v + T_);          // E*B*CAP = 8192

    // ---- scratch arena inside d_out (logits written only at the very end) ----
    float* x    = out;                                   // T*D residual stream
    float* h    = x    + (long long)T_ * D_;             // T*D
    float* qkv  = h    + (long long)T_ * D_;             // T*3D
    float* P    = qkv  + (long long)T_ * 3 * D_;         // B*H*S*S
    float* ao   = P    + (long long)B_ * H_ * S_ * S_;   // T*D
    float* ffh  = ao   + (long long)T_ * D_;             // T*G (covers T*FF)
    float* ffg  = ffh  + (long long)T_ * G_;             // T*DHID
    float* x1   = ffg  + (long long)T_ * DHID_;          // T*D
    float* t0   = x1   + (long long)T_ * D_;             // T*D
    float* xin  = t0   + (long long)T_ * D_;             // E*B*CAP*D
    float* eh   = xin  + (long long)E_ * B_ * CAP_ * D_; // E*B*CAP*G
    float* eg   = eh   + (long long)E_ * B_ * CAP_ * G_; // E*B*CAP*DHID
    float* eout = eg   + (long long)E_ * B_ * CAP_ * DHID_; // E*B*CAP*D
    // total = 100,663,296 floats <= out_size-1 = 102,928,384. OK.

    hipMemsetAsync(aux, 0, 4, stream);

    embed_kernel<<<T_, 256, 0, stream>>>(ids, wte, wpe, x);

    for (int L = 0; L < NL_; ++L) {
        // ---- attention ----
        ln_kernel<<<T_, 256, 0, stream>>>(x, ln1_g + L * D_, ln1_b + L * D_, h);
        launch_gemm<0, true, false, false>(stream, h, D_, 0,
            w_qkv + (long long)L * D_ * 3 * D_, 3 * D_, 0,
            b_qkv + (long long)L * 3 * D_, 0, nullptr,
            qkv, 3 * D_, 0, T_, 3 * D_, D_, 1);
        attn_scores_kernel<<<dim3(S_, H_, B_), 256, 0, stream>>>(qkv, P);
        attn_pv_kernel<<<dim3(S_, H_, B_), 64, 0, stream>>>(qkv, P, ao);
        launch_gemm<0, true, true, false>(stream, ao, D_, 0,
            w_ao + (long long)L * D_ * D_, D_, 0,
            b_ao + (long long)L * D_, 0, x,
            x, D_, 0, T_, D_, D_, 1);

        ln_kernel<<<T_, 256, 0, stream>>>(x, ln2_g + L * D_, ln2_b + L * D_, h);

        if (L == 0 || L == 3) {
            // ---- geglu_b: x1 = h + (rms(h)@w1+b1 -> glu) @ w2 + b2 ----
            rms_kernel<<<T_, 256, 0, stream>>>(h, ffb_g, t0);
            launch_gemm<0, true, false, false>(stream, t0, D_, 0, ffb_w1, G_, 0,
                ffb_b1, 0, nullptr, ffh, G_, 0, T_, G_, D_, 1);
            glu_kernel<<<(T_ * DHID_) / 256, 256, 0, stream>>>(ffh, ffg, T_);
            launch_gemm<0, true, true, false>(stream, ffg, DHID_, 0, ffb_w2, D_, 0,
                ffb_b2, 0, h, x1, D_, 0, T_, D_, DHID_, 1);
            // ---- gating on rms(x1) ----
            rms_kernel<<<T_, 256, 0, stream>>>(x1, moe_g, t0);
            hipMemsetAsync(red, 0, 17 * sizeof(float), stream);
            moe_gate_kernel<<<T_ / 256, 256, 0, stream>>>(t0, w_gate, idx1, idx2, g1v, g2v, red);
            aux_finalize_kernel<<<1, 1, 0, stream>>>(red, aux);
            hipMemsetAsync(slot, 0xFF, E_ * B_ * CAP_ * sizeof(int), stream);
            moe_scan_kernel<<<1, 64, 0, stream>>>(idx1, idx2, g2v, c1p, c2p, slot);
            moe_gather_kernel<<<E_ * B_ * CAP_, 256, 0, stream>>>(t0, slot, xin);
            // ---- experts (batched over gridDim.z = E) ----
            launch_gemm<0, true, false, false>(stream,
                xin, D_, (long long)B_ * CAP_ * D_,
                we1, G_, (long long)D_ * G_,
                be1, G_, nullptr,
                eh, G_, (long long)B_ * CAP_ * G_, B_ * CAP_, G_, D_, E_);
            glu_kernel<<<(E_ * B_ * CAP_ * DHID_) / 256, 256, 0, stream>>>(eh, eg, E_ * B_ * CAP_);
            launch_gemm<0, true, false, false>(stream,
                eg, DHID_, (long long)B_ * CAP_ * DHID_,
                we2, D_, (long long)DHID_ * D_,
                be2, D_, nullptr,
                eout, D_, (long long)B_ * CAP_ * D_, B_ * CAP_, D_, DHID_, E_);
            moe_combine_kernel<<<T_, 256, 0, stream>>>(eout, idx1, idx2, c1p, c2p, g1v, g2v, x1);
            // x += x2 (x1 now holds x2)
            add_kernel<<<(T_ * D_) / 256, 256, 0, stream>>>(x, x1, T_ * D_);
            // ---- geglu_a on x2, residual into x ----
            rms_kernel<<<T_, 256, 0, stream>>>(x1, ffa_g, t0);
            launch_gemm<0, true, false, false>(stream, t0, D_, 0, ffa_w1, G_, 0,
                ffa_b1, 0, nullptr, ffh, G_, 0, T_, G_, D_, 1);
            glu_kernel<<<(T_ * DHID_) / 256, 256, 0, stream>>>(ffh, ffg, T_);
            launch_gemm<0, true, true, false>(stream, ffg, DHID_, 0, ffa_w2, D_, 0,
                ffa_b2, 0, x, x, D_, 0, T_, D_, DHID_, 1);
        } else {
            // ---- dense MLP ----
            launch_gemm<1, true, false, false>(stream, h, D_, 0,
                w_fc + (long long)L * D_ * FF_, FF_, 0,
                b_fc + (long long)L * FF_, 0, nullptr,
                ffh, FF_, 0, T_, FF_, D_, 1);
            launch_gemm<0, true, true, false>(stream, ffh, FF_, 0,
                w_mp + (long long)L * FF_ * D_, D_, 0,
                b_mp + (long long)L * D_, 0, x,
                x, D_, 0, T_, D_, FF_, 1);
        }
    }

    // ---- final LN (to ws) then logits = xf @ wte^T into d_out ----
    ln_kernel<<<T_, 256, 0, stream>>>(x, lnf_g, lnf_b, xf);
    launch_gemm<0, false, false, true>(stream, xf, D_, 0, wte, D_, 0,
        nullptr, 0, nullptr, out, V_, 0, T_, V_, D_, 1);
    write_aux_kernel<<<1, 1, 0, stream>>>(out + (long long)T_ * V_, aux);
}